// Round 14
// baseline (2089.728 us; speedup 1.0000x reference)
//
#include <hip/hip_runtime.h>

#define T_N 4096
#define B_N 64
#define I_N 128
#define H_N 128
#define BH  (B_N * H_N)
#define NB2 16     // batches per scan block (MFMA N-dim = batch cols)
#define NPAD 136   // fp16 row stride for h_lds (128 + 8 pad; 272B, 16B-aligned)

typedef _Float16 half8  __attribute__((ext_vector_type(8)));
typedef __fp16   fp16x2 __attribute__((ext_vector_type(2)));
typedef float    f32x4  __attribute__((ext_vector_type(4)));

// ---------------------------------------------------------------------------
// Phase 1: xp = x @ W_ih^T + b_ih -> into out (in-place with phase 2).
// Unchanged from R2-R12 (~70 us).
// ---------------------------------------------------------------------------
__global__ __launch_bounds__(256) void xproj_kernel(
    const float* __restrict__ x, const float* __restrict__ Wih,
    const float* __restrict__ bih, float* __restrict__ xp)
{
    __shared__ float wt[I_N][H_N];   // wt[k][j] = Wih[j][k], 64 KB
    const int tid = threadIdx.x;

    {
        const float4* w4 = (const float4*)Wih;
        #pragma unroll
        for (int it = 0; it < 16; ++it) {
            int i = tid * 16 + it;          // 0..4095 float4s
            float4 v = w4[i];
            int r = i >> 5;                 // W row j
            int k = (i & 31) << 2;          // k base
            wt[k + 0][r] = v.x;
            wt[k + 1][r] = v.y;
            wt[k + 2][r] = v.z;
            wt[k + 3][r] = v.w;
        }
    }
    __syncthreads();

    const int  tx   = tid & 15;
    const int  ty   = tid >> 4;
    const long row0 = (long)blockIdx.x * 128;
    const float* xbase = x + (row0 + ty * 8) * I_N;

    float acc[8][8];
    #pragma unroll
    for (int r = 0; r < 8; ++r)
        #pragma unroll
        for (int c = 0; c < 8; ++c) acc[r][c] = 0.0f;

    #pragma unroll 2
    for (int k4 = 0; k4 < I_N / 4; ++k4) {
        float4 xv[8];
        #pragma unroll
        for (int r = 0; r < 8; ++r)
            xv[r] = *(const float4*)(xbase + r * I_N + k4 * 4);

        #pragma unroll
        for (int kk = 0; kk < 4; ++kk) {
            int k = k4 * 4 + kk;
            float4 w0 = *(const float4*)&wt[k][tx * 4];
            float4 w1 = *(const float4*)&wt[k][64 + tx * 4];
            #pragma unroll
            for (int r = 0; r < 8; ++r) {
                float xk = (kk == 0) ? xv[r].x : (kk == 1) ? xv[r].y
                         : (kk == 2) ? xv[r].z : xv[r].w;
                acc[r][0] = fmaf(xk, w0.x, acc[r][0]);
                acc[r][1] = fmaf(xk, w0.y, acc[r][1]);
                acc[r][2] = fmaf(xk, w0.z, acc[r][2]);
                acc[r][3] = fmaf(xk, w0.w, acc[r][3]);
                acc[r][4] = fmaf(xk, w1.x, acc[r][4]);
                acc[r][5] = fmaf(xk, w1.y, acc[r][5]);
                acc[r][6] = fmaf(xk, w1.z, acc[r][6]);
                acc[r][7] = fmaf(xk, w1.w, acc[r][7]);
            }
        }
    }

    float4 b0 = *(const float4*)(bih + tx * 4);
    float4 b1 = *(const float4*)(bih + 64 + tx * 4);
    #pragma unroll
    for (int r = 0; r < 8; ++r) {
        long row = row0 + ty * 8 + r;
        float4 o0, o1;
        o0.x = acc[r][0] + b0.x;  o0.y = acc[r][1] + b0.y;
        o0.z = acc[r][2] + b0.z;  o0.w = acc[r][3] + b0.w;
        o1.x = acc[r][4] + b1.x;  o1.y = acc[r][5] + b1.y;
        o1.z = acc[r][6] + b1.z;  o1.w = acc[r][7] + b1.w;
        *(float4*)(xp + row * H_N + tx * 4)      = o0;
        *(float4*)(xp + row * H_N + 64 + tx * 4) = o1;
    }
}

// ---------------------------------------------------------------------------
// Phase 2 (R14 = R13 + compile fix): MFMA scan, re-tiled. 4 blocks x 16
// batches, 256 threads = 4 waves. Each wave owns j-range [32*wv, 32*wv+32)
// = 2 j-tiles; per step: 4 shared B-frag b128 reads (h^T, reused by BOTH
// tiles -> block LDS reads halve vs R12), 8 MFMA as two 2-deep chains per
// tile with the C-input SEEDED by xp+b_hh, 8 tanh, cvt_pkrtz pack, 2 x b64
// h-writes, lgkmcnt(0) + 4-wave barrier; out-stores post-barrier. Layouts
// identical to R12 (HW-verified): A row = lane&15, k = 8*(lane>>4)+i;
// B col = lane&15; C/D col = lane&15 = batch, row = 4*(lane>>4)+reg = j.
// ---------------------------------------------------------------------------
__device__ __forceinline__ float tanh_pade(float x) {
    float u = x * x;
    float n = fmaf(u, u + 105.0f, 945.0f);              // u^2 + 105u + 945
    float d = fmaf(u, fmaf(15.0f, u, 420.0f), 945.0f);  // 15u^2 + 420u + 945
    float t = x * n * __builtin_amdgcn_rcpf(d);
    return fminf(1.0f, fmaxf(-1.0f, t));                // v_med3_f32
}

__device__ __forceinline__ unsigned pack2(float a, float b) {
    fp16x2 p = __builtin_amdgcn_cvt_pkrtz(a, b);
    return __builtin_bit_cast(unsigned, p);
}

__global__ __launch_bounds__(256, 1) void scan_mfma(
    const float* __restrict__ Whh, const float* __restrict__ bhh,
    const float* __restrict__ h0, float* __restrict__ out)
{
    const int tid  = threadIdx.x;
    const int lane = tid & 63;
    const int wv   = tid >> 6;              // 0..3
    const int r16  = lane & 15;             // batch col (B/C); j row (A)
    const int kg   = lane >> 4;             // 0..3 k/reg group
    const int jb   = wv * 32;               // wave j-base (2 tiles: jb, jb+16)
    const int b    = blockIdx.x * NB2 + r16;

    __shared__ __align__(16) _Float16 hbuf[2][NB2][NPAD];

    // A-frags: af[t][c] = W[jb+16t+r16][32c + 8kg .. +8] fp32->fp16, static.
    half8 af[2][4];
    #pragma unroll
    for (int t = 0; t < 2; ++t) {
        #pragma unroll
        for (int c = 0; c < 4; ++c) {
            const float* wp = Whh + (size_t)(jb + 16 * t + r16) * H_N + 32 * c + 8 * kg;
            float4 wa = *(const float4*)wp;
            float4 wb = *(const float4*)(wp + 4);
            half8 h;
            h[0] = (_Float16)wa.x; h[1] = (_Float16)wa.y;
            h[2] = (_Float16)wa.z; h[3] = (_Float16)wa.w;
            h[4] = (_Float16)wb.x; h[5] = (_Float16)wb.y;
            h[6] = (_Float16)wb.z; h[7] = (_Float16)wb.w;
            af[t][c] = h;
        }
    }

    // Lane's outputs: tile t -> j = jb + 16t + 4kg + {0..3} (consecutive).
    const float4 bh0 = *(const float4*)(bhh + jb + 4 * kg);
    const float4 bh1 = *(const float4*)(bhh + jb + 16 + 4 * kg);

    // Stage h0 -> hbuf[0][batch][j] fp16 (each thread: 8 j of one batch).
    {
        int bt = tid >> 4, j8 = (tid & 15) * 8;
        const float* hp = h0 + (size_t)(blockIdx.x * NB2 + bt) * H_N + j8;
        float4 a = *(const float4*)hp;
        float4 c = *(const float4*)(hp + 4);
        half8 hh;
        hh[0] = (_Float16)a.x; hh[1] = (_Float16)a.y;
        hh[2] = (_Float16)a.z; hh[3] = (_Float16)a.w;
        hh[4] = (_Float16)c.x; hh[5] = (_Float16)c.y;
        hh[6] = (_Float16)c.z; hh[7] = (_Float16)c.w;
        *(half8*)&hbuf[0][bt][j8] = hh;
    }

    const float* xq0 = out + (size_t)b * H_N + jb + 4 * kg;
    const float* xq1 = xq0 + 16;
    float*       oq0 = out + (size_t)b * H_N + jb + 4 * kg;
    float*       oq1 = oq0 + 16;

    float4 xv0[4], xv1[4];
    #pragma unroll
    for (int d = 0; d < 4; ++d) {
        xv0[d] = *(const float4*)(xq0 + (size_t)d * BH);
        xv1[d] = *(const float4*)(xq1 + (size_t)d * BH);
    }

    __syncthreads();

#define STEP(T0, D, CUR, NXT) do {                                            \
        const _Float16* hb = &hbuf[CUR][r16][0];                              \
        half8 bf0 = *(const half8*)(hb + 8 * kg);                             \
        half8 bf1 = *(const half8*)(hb + 32 + 8 * kg);                        \
        half8 bf2 = *(const half8*)(hb + 64 + 8 * kg);                        \
        half8 bf3 = *(const half8*)(hb + 96 + 8 * kg);                        \
        f32x4 s0, s1, u0, u1;                                                 \
        s0[0] = xv0[D].x + bh0.x; s0[1] = xv0[D].y + bh0.y;                   \
        s0[2] = xv0[D].z + bh0.z; s0[3] = xv0[D].w + bh0.w;                   \
        s1[0] = xv1[D].x + bh1.x; s1[1] = xv1[D].y + bh1.y;                   \
        s1[2] = xv1[D].z + bh1.z; s1[3] = xv1[D].w + bh1.w;                   \
        u0[0] = u0[1] = u0[2] = u0[3] = 0.f;                                  \
        u1[0] = u1[1] = u1[2] = u1[3] = 0.f;                                  \
        s0 = __builtin_amdgcn_mfma_f32_16x16x32_f16(af[0][0], bf0, s0, 0, 0, 0); \
        u0 = __builtin_amdgcn_mfma_f32_16x16x32_f16(af[0][2], bf2, u0, 0, 0, 0); \
        s1 = __builtin_amdgcn_mfma_f32_16x16x32_f16(af[1][0], bf0, s1, 0, 0, 0); \
        u1 = __builtin_amdgcn_mfma_f32_16x16x32_f16(af[1][2], bf2, u1, 0, 0, 0); \
        s0 = __builtin_amdgcn_mfma_f32_16x16x32_f16(af[0][1], bf1, s0, 0, 0, 0); \
        u0 = __builtin_amdgcn_mfma_f32_16x16x32_f16(af[0][3], bf3, u0, 0, 0, 0); \
        s1 = __builtin_amdgcn_mfma_f32_16x16x32_f16(af[1][1], bf1, s1, 0, 0, 0); \
        u1 = __builtin_amdgcn_mfma_f32_16x16x32_f16(af[1][3], bf3, u1, 0, 0, 0); \
        float4 hv0, hv1;                                                      \
        hv0.x = tanh_pade(s0[0] + u0[0]); hv0.y = tanh_pade(s0[1] + u0[1]);   \
        hv0.z = tanh_pade(s0[2] + u0[2]); hv0.w = tanh_pade(s0[3] + u0[3]);   \
        hv1.x = tanh_pade(s1[0] + u1[0]); hv1.y = tanh_pade(s1[1] + u1[1]);   \
        hv1.z = tanh_pade(s1[2] + u1[2]); hv1.w = tanh_pade(s1[3] + u1[3]);   \
        uint2 pk0, pk1;                                                       \
        pk0.x = pack2(hv0.x, hv0.y);  pk0.y = pack2(hv0.z, hv0.w);            \
        pk1.x = pack2(hv1.x, hv1.y);  pk1.y = pack2(hv1.z, hv1.w);            \
        *(uint2*)&hbuf[NXT][r16][jb + 4 * kg]      = pk0;                     \
        *(uint2*)&hbuf[NXT][r16][jb + 16 + 4 * kg] = pk1;                     \
        if ((T0) + 4 < T_N) {                                                 \
            xv0[D] = *(const float4*)(xq0 + (size_t)((T0) + 4) * BH);         \
            xv1[D] = *(const float4*)(xq1 + (size_t)((T0) + 4) * BH);         \
        }                                                                     \
        asm volatile("s_waitcnt lgkmcnt(0)" ::: "memory");                    \
        __builtin_amdgcn_s_barrier();                                         \
        *(float4*)(oq0 + (size_t)(T0) * BH) = hv0;                            \
        *(float4*)(oq1 + (size_t)(T0) * BH) = hv1;                            \
        if ((T0) == T_N - 1) {                                                \
            *(float4*)(oq0 + (size_t)T_N * BH) = hv0;                         \
            *(float4*)(oq1 + (size_t)T_N * BH) = hv1;                         \
        }                                                                     \
        asm volatile("" ::: "memory");                                        \
    } while (0)

    for (int t = 0; t < T_N; t += 4) {
        STEP(t + 0, 0, 0, 1);
        STEP(t + 1, 1, 1, 0);
        STEP(t + 2, 2, 0, 1);
        STEP(t + 3, 3, 1, 0);
    }
#undef STEP
}

extern "C" void kernel_launch(void* const* d_in, const int* in_sizes, int n_in,
                              void* d_out, int out_size, void* d_ws, size_t ws_size,
                              hipStream_t stream) {
    const float* x   = (const float*)d_in[0];
    const float* h0  = (const float*)d_in[1];
    const float* Wih = (const float*)d_in[2];
    const float* Whh = (const float*)d_in[3];
    const float* bih = (const float*)d_in[4];
    const float* bhh = (const float*)d_in[5];
    float* out = (float*)d_out;

    xproj_kernel<<<dim3((T_N * B_N) / 128), 256, 0, stream>>>(x, Wih, bih, out);
    scan_mfma<<<dim3(B_N / NB2), 256, 0, stream>>>(Whh, bhh, h0, out);
}